// Round 14
// baseline (534.107 us; speedup 1.0000x reference)
//
#include <hip/hip_runtime.h>

typedef __bf16 bf16;
typedef __bf16 bf16x2 __attribute__((ext_vector_type(2)));
typedef __bf16 bf16x4 __attribute__((ext_vector_type(4)));
typedef __bf16 bf16x8 __attribute__((ext_vector_type(8)));
typedef float  f32x4  __attribute__((ext_vector_type(4)));

#define H_    24
#define D_    128
#define HID_  3072
#define SIMG_ 2048
#define STXT_ 512
#define STOT_ 2560
#define EPS_  1e-5f
#define SCALE_ 0.08838834764831845f   // 1/sqrt(128)
#define HH_   ((size_t)HID_*HID_)

// ---- async global->LDS, 16B per lane (wave-uniform dest base + lane*16)
typedef __attribute__((address_space(3))) unsigned int lds_uint;
typedef const __attribute__((address_space(1))) unsigned int glb_uint;
__device__ __forceinline__ void gll16(const void* g, void* l){
  __builtin_amdgcn_global_load_lds((glb_uint*)g, (lds_uint*)l, 16, 0, 0);
}

__device__ inline bf16x8 frag8f(const float* __restrict__ p){
  const f32x4 a = *(const f32x4*)p;
  const f32x4 b = *(const f32x4*)(p + 4);
  bf16x8 r;
  r[0]=(bf16)a[0]; r[1]=(bf16)a[1]; r[2]=(bf16)a[2]; r[3]=(bf16)a[3];
  r[4]=(bf16)b[0]; r[5]=(bf16)b[1]; r[6]=(bf16)b[2]; r[7]=(bf16)b[3];
  return r;
}

__device__ __forceinline__ void cvt8(const float* __restrict__ s, bf16* __restrict__ d, int i){
  const f32x4 a = *(const f32x4*)(s + i);
  const f32x4 b = *(const f32x4*)(s + i + 4);
  bf16x8 o;
  o[0]=(bf16)a[0]; o[1]=(bf16)a[1]; o[2]=(bf16)a[2]; o[3]=(bf16)a[3];
  o[4]=(bf16)b[0]; o[5]=(bf16)b[1]; o[6]=(bf16)b[2]; o[7]=(bf16)b[3];
  *(bf16x8*)(d + i) = o;
}

// ================= k_prep: 48 ip-gemm blocks first + 2048 persistent grid-strided
// conversion blocks (r11-proven).
#define CONV_BLK 2048
__global__ __launch_bounds__(256) void k_prep(
    const float* __restrict__ HS, const float* __restrict__ ENC,
    const float* __restrict__ W0, const float* __restrict__ W1,
    const float* __restrict__ W2, const float* __restrict__ W3,
    const float* __restrict__ W4, const float* __restrict__ W5,
    const float* __restrict__ W6, const float* __restrict__ W7,
    const float* __restrict__ IMG,
    const float* __restrict__ Wkip, const float* __restrict__ Wvip,
    bf16* __restrict__ HSb, bf16* __restrict__ ENCb, bf16* __restrict__ Wb8,
    float* __restrict__ Kip, float* __restrict__ Vip)
{
  __shared__ float tile[4][128];
  const int bx = (int)blockIdx.x;
  const int t = (int)threadIdx.x;
  if (bx < 48){
    const bool isV = (bx >= 24);
    const int h = bx % 24;
    const float* Wm = isV ? Wvip : Wkip;
    const int w = t >> 6, l = t & 63;
    const int lr = l & 15, lg = l >> 4;
    const int col0 = h*128 + w*32;
    f32x4 acc0 = {}, acc1 = {};
    const float* arow = IMG + (size_t)((lr < 4) ? lr : 0)*HID_;
    const float* wr0 = Wm + (size_t)(col0 + lr)*HID_;
    const float* wr1 = Wm + (size_t)(col0 + 16 + lr)*HID_;
    for (int k0 = 0; k0 < HID_; k0 += 32){
      const bf16x8 af = frag8f(arow + k0 + lg*8);
      acc0 = __builtin_amdgcn_mfma_f32_16x16x32_bf16(af, frag8f(wr0 + k0 + lg*8), acc0, 0, 0, 0);
      acc1 = __builtin_amdgcn_mfma_f32_16x16x32_bf16(af, frag8f(wr1 + k0 + lg*8), acc1, 0, 0, 0);
    }
    if (lg == 0){
      #pragma unroll
      for (int r = 0; r < 4; r++){
        tile[r][w*32 + lr]      = acc0[r];
        tile[r][w*32 + 16 + lr] = acc1[r];
      }
    }
    __syncthreads();
    if (isV){
      const int e = t*2;
      const int j = e >> 7, d = e & 127;
      Vip[(size_t)(h*4 + j)*D_ + d]     = tile[j][d];
      Vip[(size_t)(h*4 + j)*D_ + d + 1] = tile[j][d + 1];
    } else {
      const float v0 = tile[w][2*l], v1 = tile[w][2*l + 1];
      float ss = v0*v0 + v1*v1;
      #pragma unroll
      for (int m = 1; m < 64; m <<= 1) ss += __shfl_xor(ss, m);
      const float rk = rsqrtf(ss*(1.0f/128.0f) + EPS_);
      Kip[(size_t)(h*4 + w)*D_ + 2*l]     = v0*rk;
      Kip[(size_t)(h*4 + w)*D_ + 2*l + 1] = v1*rk;
    }
  } else {
    for (int c = bx - 48; c < 20352; c += CONV_BLK){
      const float* s; bf16* d; int base;
      if (c < 1536){ s = HS;  d = HSb;  base = c*4096; }
      else if (c < 1920){ s = ENC; d = ENCb; base = (c - 1536)*4096; }
      else {
        const int idx = c - 1920;
        const int wi = idx / 2304;
        s = (wi==0)?W0:(wi==1)?W1:(wi==2)?W2:(wi==3)?W3:(wi==4)?W4:(wi==5)?W5:(wi==6)?W6:W7;
        d = Wb8 + (size_t)wi*HH_;
        base = (idx % 2304)*4096;
      }
      const int i = base + t*16;
      cvt8(s, d, i);
      cvt8(s, d, i + 8);
    }
  }
}

// ================= 8-wave, BM=128 x BN=256, BK=64, triple-buffered counted-vmcnt
// pipeline (r6-proven: 201-211 us QKV, 0 bank conflicts).
#define MFMA_ __builtin_amdgcn_mfma_f32_16x16x32_bf16
#define MM(bfr, n) \
    acc[0][n]=MFMA_(af0,bfr,acc[0][n],0,0,0); acc[1][n]=MFMA_(af1,bfr,acc[1][n],0,0,0); \
    acc[2][n]=MFMA_(af2,bfr,acc[2][n],0,0,0); acc[3][n]=MFMA_(af3,bfr,acc[3][n],0,0,0);
#define WAIT6  asm volatile("s_waitcnt vmcnt(6)" ::: "memory")
#define WAIT0  asm volatile("s_waitcnt vmcnt(0)" ::: "memory")
#define NOWAIT (void)0

__device__ __forceinline__ void gemm8_core(
    const bf16* __restrict__ A, const bf16* __restrict__ W,
    int mb, int nb,
    f32x4 (&acc)[4][4],
    bf16 (&Al)[3][128][64],
    bf16 (&Bl)[3][256][64])
{
  const int t = (int)threadIdx.x;
  const int w = t >> 6, l = t & 63;
  const int lr = l & 15, lg = l >> 4;
  const int wr = w >> 2, wc = w & 3;
  const int srow = t >> 3;
  const int soff = ((t & 7) ^ (srow & 7)) * 8;

  const bf16* Abase = A + (size_t)(mb + srow)*HID_ + soff;
  const bf16* Wbase = W + (size_t)(nb + srow)*HID_ + soff;

#define SA(buf, tt, i) gll16(Abase + (size_t)(i)*64*HID_ + (tt)*64, &Al[buf][0][0] + (i)*4096 + t*8)
#define SB(buf, tt, i) gll16(Wbase + (size_t)(i)*64*HID_ + (tt)*64, &Bl[buf][0][0] + (i)*4096 + t*8)

  const int arow_ = wr*64 + lr;
  const int brow_ = wc*64 + lr;
  const int sx = lr & 7;

  SA(0,0,0); SA(0,0,1); SB(0,0,0); SB(0,0,1); SB(0,0,2); SB(0,0,3);
  SA(1,1,0); SA(1,1,1); SB(1,1,0); SB(1,1,1); SB(1,1,2); SB(1,1,3);
  WAIT6;
  __builtin_amdgcn_s_barrier();

#define TILE(C, NXT, TT, PRE, TW)                                            \
  {                                                                          \
    const int s0_ = (lg^sx)*8, s1_ = ((4+lg)^sx)*8;                          \
    bf16x8 af0,af1,af2,af3,b0,b1;                                            \
    af0=*(const bf16x8*)&Al[C][arow_   ][s0_];                               \
    af1=*(const bf16x8*)&Al[C][arow_+16][s0_];                               \
    af2=*(const bf16x8*)&Al[C][arow_+32][s0_];                               \
    af3=*(const bf16x8*)&Al[C][arow_+48][s0_];                               \
    b0 =*(const bf16x8*)&Bl[C][brow_   ][s0_];                               \
    b1 =*(const bf16x8*)&Bl[C][brow_+16][s0_];                               \
    if (PRE){ SA(NXT,(TT)+2,0); SA(NXT,(TT)+2,1); }                          \
    __builtin_amdgcn_s_setprio(1); MM(b0,0) MM(b1,1)                         \
    __builtin_amdgcn_s_setprio(0);                                           \
    b0 =*(const bf16x8*)&Bl[C][brow_+32][s0_];                               \
    b1 =*(const bf16x8*)&Bl[C][brow_+48][s0_];                               \
    if (PRE){ SB(NXT,(TT)+2,0); SB(NXT,(TT)+2,1); }                          \
    __builtin_amdgcn_s_setprio(1); MM(b0,2) MM(b1,3)                         \
    __builtin_amdgcn_s_setprio(0);                                           \
    af0=*(const bf16x8*)&Al[C][arow_   ][s1_];                               \
    af1=*(const bf16x8*)&Al[C][arow_+16][s1_];                               \
    af2=*(const bf16x8*)&Al[C][arow_+32][s1_];                               \
    af3=*(const bf16x8*)&Al[C][arow_+48][s1_];                               \
    b0 =*(const bf16x8*)&Bl[C][brow_   ][s1_];                               \
    b1 =*(const bf16x8*)&Bl[C][brow_+16][s1_];                               \
    if (PRE){ SB(NXT,(TT)+2,2); SB(NXT,(TT)+2,3); }                          \
    __builtin_amdgcn_s_setprio(1); MM(b0,0) MM(b1,1)                         \
    __builtin_amdgcn_s_setprio(0);                                           \
    b0 =*(const bf16x8*)&Bl[C][brow_+32][s1_];                               \
    b1 =*(const bf16x8*)&Bl[C][brow_+48][s1_];                               \
    __builtin_amdgcn_s_setprio(1); MM(b0,2) MM(b1,3)                         \
    __builtin_amdgcn_s_setprio(0);                                           \
    TW;                                                                      \
    __builtin_amdgcn_s_barrier();                                            \
  }

  for (int base = 0; base < 45; base += 3){
    TILE(0, 2, base,   true, WAIT6);
    TILE(1, 0, base+1, true, WAIT6);
    TILE(2, 1, base+2, true, WAIT6);
  }
  TILE(0, 2, 45, true,  WAIT6);
  TILE(1, 0, 46, false, WAIT0);
  TILE(2, 1, 47, false, NOWAIT);
#undef TILE
#undef SA
#undef SB
}

// ---------------- QKV instantiation: grid 720 (1-D, XCD-chunked swizzle).
__global__ __launch_bounds__(512, 1) void k_gemm8_qkv(
    const bf16* __restrict__ Ahid, const bf16* __restrict__ Aenc,
    const bf16* __restrict__ Wb,
    const float* bq, const float* bk, const float* bv,
    const float* baq, const float* bak, const float* bav,
    bf16* Cq, bf16* Ck, bf16* Cv, bf16* Ceq, bf16* Cek, bf16* Cev)
{
  __shared__ __align__(16) bf16 Al[3][128][64];
  __shared__ __align__(16) bf16 Bl[3][256][64];
  const int lin = (int)blockIdx.x;
  const int work = (lin & 7)*90 + (lin >> 3);
  const int mt = work / 36;
  const int ct = work % 36;
  const int which = ct % 3;
  const int nb = (ct/3)*256;
  const int enc = (mt >= 16) ? 1 : 0;
  const int mb = (enc ? (mt - 16) : mt)*128;
  const bf16* A = enc ? Aenc : Ahid;
  const int widx = which + enc*3;
  const bf16* W = Wb + (size_t)widx*HH_;
  const float* bias = (which==0) ? (enc?baq:bq) : (which==1) ? (enc?bak:bk) : (enc?bav:bv);
  bf16* Cm = (which==0) ? (enc?Ceq:Cq) : (which==1) ? (enc?Cek:Ck) : (enc?Cev:Cv);

  f32x4 acc[4][4] = {};
  gemm8_core(A, W, mb, nb, acc, Al, Bl);

  const int w = (int)(threadIdx.x >> 6), l = (int)(threadIdx.x & 63u);
  const int lr = l & 15, lg = l >> 4;
  const int wr = w >> 2, wc = w & 3;
  #pragma unroll
  for (int nf = 0; nf < 4; nf++){
    const int col = nb + wc*64 + nf*16 + lr;
    const float bvl = bias[col];
    #pragma unroll
    for (int m = 0; m < 4; m++){
      #pragma unroll
      for (int r = 0; r < 4; r++){
        const int row = mb + wr*64 + m*16 + lg*4 + r;
        Cm[(size_t)row*HID_ + col] = (bf16)(acc[m][nf][r] + bvl);
      }
    }
  }
}

// ---------------- Output instantiation: grid 240 (1-D). fp32 out.
__global__ __launch_bounds__(512, 1) void k_gemm8_out(
    const bf16* __restrict__ Ahid, const bf16* __restrict__ Aenc,
    const bf16* __restrict__ Wb,
    const float* bo, const float* bao, float* __restrict__ outp)
{
  __shared__ __align__(16) bf16 Al[3][128][64];
  __shared__ __align__(16) bf16 Bl[3][256][64];
  const int lin = (int)blockIdx.x;
  const int work = (lin & 7)*30 + (lin >> 3);
  const int mt = work / 12;
  const int nb = (work % 12)*256;
  const int enc = (mt >= 16) ? 1 : 0;
  const int mb = (enc ? (mt - 16) : mt)*128;
  const bf16* A = enc ? Aenc : Ahid;
  const bf16* W = Wb + (size_t)(enc ? 7 : 6)*HH_;
  const float* bias = enc ? bao : bo;
  float* C = outp + (enc ? (size_t)SIMG_*HID_ : 0);

  f32x4 acc[4][4] = {};
  gemm8_core(A, W, mb, nb, acc, Al, Bl);

  const int w = (int)(threadIdx.x >> 6), l = (int)(threadIdx.x & 63u);
  const int lr = l & 15, lg = l >> 4;
  const int wr = w >> 2, wc = w & 3;
  #pragma unroll
  for (int nf = 0; nf < 4; nf++){
    const int col = nb + wc*64 + nf*16 + lr;
    const float bvl = bias[col];
    #pragma unroll
    for (int m = 0; m < 4; m++){
      #pragma unroll
      for (int r = 0; r < 4; r++){
        const int row = mb + wr*64 + m*16 + lg*4 + r;
        C[(size_t)row*HID_ + col] = acc[m][nf][r] + bvl;
      }
    }
  }
}

// ================= k_finish_qk2: persistent grid-strided (2048 blocks, 8/CU).
// RMSNorm + RoPE for q,k; fused ip-attention on hid rows. No LDS.
#define FIN_BLK 2048
__global__ __launch_bounds__(256) void k_finish_qk2(
    const bf16* __restrict__ rawQ, const bf16* __restrict__ rawK,
    const bf16* __restrict__ rawEQ, const bf16* __restrict__ rawEK,
    const float* __restrict__ cosT, const float* __restrict__ sinT,
    const float* __restrict__ Kip, const float* __restrict__ Vip,
    bf16* __restrict__ Qh, bf16* __restrict__ Kh, bf16* __restrict__ ipOut)
{
  const int wv = (int)(threadIdx.x >> 6);
  const int l = (int)(threadIdx.x & 63u);
  const int d0 = 2*l, d1 = 2*l + 1;
  for (int b = (int)blockIdx.x; b < 15360; b += FIN_BLK){
    const int wid = b*4 + wv;
    const int s = wid / H_;
    const int h = wid % H_;
    const bf16 *sq_, *sk_;
    if (s < STXT_){
      const size_t off = (size_t)s*HID_ + h*D_;
      sq_ = rawEQ + off; sk_ = rawEK + off;
    } else {
      const size_t off = (size_t)(s - STXT_)*HID_ + h*D_;
      sq_ = rawQ + off; sk_ = rawK + off;
    }
    float q0 = sq_[d0], q1 = sq_[d1];
    float k0 = sk_[d0], k1 = sk_[d1];
    float ssq = q0*q0 + q1*q1;
    float ssk = k0*k0 + k1*k1;
    #pragma unroll
    for (int m = 1; m < 64; m <<= 1){ ssq += __shfl_xor(ssq, m); ssk += __shfl_xor(ssk, m); }
    const float rq = rsqrtf(ssq*(1.0f/128.0f) + EPS_);
    const float rk = rsqrtf(ssk*(1.0f/128.0f) + EPS_);
    q0 *= rq; q1 *= rq; k0 *= rk; k1 *= rk;
    const float c0 = cosT[(size_t)s*D_ + d0], c1 = cosT[(size_t)s*D_ + d1];
    const float s0 = sinT[(size_t)s*D_ + d0], s1 = sinT[(size_t)s*D_ + d1];
    const float qo0 = q0*c0 - q1*s0, qo1 = q1*c1 + q0*s1;
    const float ko0 = k0*c0 - k1*s0, ko1 = k1*c1 + k0*s1;
    const size_t qoff = ((size_t)h*STOT_ + s)*D_ + d0;
    Qh[qoff] = (bf16)qo0; Qh[qoff + 1] = (bf16)qo1;
    Kh[qoff] = (bf16)ko0; Kh[qoff + 1] = (bf16)ko1;

    if (s >= STXT_){
      const float* kb = Kip + (size_t)h*4*D_;
      const float* vb = Vip + (size_t)h*4*D_;
      float sc[4];
      #pragma unroll
      for (int j = 0; j < 4; j++) sc[j] = q0*kb[j*D_ + d0] + q1*kb[j*D_ + d1];
      #pragma unroll
      for (int m = 1; m < 64; m <<= 1){
        #pragma unroll
        for (int j = 0; j < 4; j++) sc[j] += __shfl_xor(sc[j], m);
      }
      const float mx = fmaxf(fmaxf(sc[0], sc[1]), fmaxf(sc[2], sc[3]));
      float p[4], ps = 0.f;
      #pragma unroll
      for (int j = 0; j < 4; j++){ p[j] = __expf((sc[j] - mx)*SCALE_); ps += p[j]; }
      const float inv = 1.0f/ps;
      float o0 = 0.f, o1 = 0.f;
      #pragma unroll
      for (int j = 0; j < 4; j++){ o0 += p[j]*vb[j*D_ + d0]; o1 += p[j]*vb[j*D_ + d1]; }
      const size_t dst = (size_t)(s - STXT_)*HID_ + h*D_;
      ipOut[dst + d0] = (bf16)(o0*inv);
      ipOut[dst + d1] = (bf16)(o1*inv);
    }
  }
}

// ---------------- V transpose: raw[E]V [s][h*128+d] -> Vt[h][d][s], LDS tiled.
__global__ __launch_bounds__(256) void k_vtrans(
    const bf16* __restrict__ rawV, const bf16* __restrict__ rawEV,
    bf16* __restrict__ Vt)
{
  __shared__ bf16 lt[128*130];
  const int t = (int)threadIdx.x;
  const int stile = (int)blockIdx.x*128;
  const int h = (int)blockIdx.y;
  #pragma unroll
  for (int i = 0; i < 8; i++){
    const int sl = i*16 + (t >> 4);
    const int s = stile + sl;
    const bf16* src = (s < STXT_) ? (rawEV + (size_t)s*HID_) : (rawV + (size_t)(s - STXT_)*HID_);
    const bf16x8 v = *(const bf16x8*)(src + h*D_ + (t & 15)*8);
    #pragma unroll
    for (int j = 0; j < 8; j++) lt[((t & 15)*8 + j)*130 + sl] = v[j];
  }
  __syncthreads();
  #pragma unroll
  for (int j = 0; j < 4; j++){
    const int d = j*32 + (t >> 3);
    const int s0 = (t & 7)*16;
    bf16x8 a, b;
    #pragma unroll
    for (int k = 0; k < 4; k++){
      const bf16x2 p = *(const bf16x2*)(lt + d*130 + s0 + 2*k);
      a[2*k] = p[0]; a[2*k+1] = p[1];
    }
    #pragma unroll
    for (int k = 0; k < 4; k++){
      const bf16x2 p = *(const bf16x2*)(lt + d*130 + s0 + 8 + 2*k);
      b[2*k] = p[0]; b[2*k+1] = p[1];
    }
    bf16* dst = Vt + ((size_t)h*D_ + d)*STOT_ + stile + s0;
    *(bf16x8*)dst = a;
    *(bf16x8*)(dst + 8) = b;
  }
}

// ---------------- Flash attention v3 + fused ip add + T13 defer-max. Grid 480 1-D.
__global__ __launch_bounds__(256, 2) void k_flash3(
    const bf16* __restrict__ Q, const bf16* __restrict__ K,
    const bf16* __restrict__ Vt, const bf16* __restrict__ ipOut,
    bf16* __restrict__ attnOut)
{
  __shared__ __align__(16) bf16 Ks[2][64*128];
  __shared__ __align__(16) bf16 Vs[2][128*64];
  __shared__ __align__(16) bf16 plds[4][32*64];
  const int t = (int)threadIdx.x;
  const int w = t >> 6, l = t & 63;
  const int lr = l & 15, lg = l >> 4;
  const int lin = (int)blockIdx.x;
  const int work = (lin & 7)*60 + (lin >> 3);
  const int h = work / 20;
  const int qbase = (work % 20)*128 + w*32;
  const bf16* Qh = Q  + (size_t)h*STOT_*D_;
  const bf16* Kh = K  + (size_t)h*STOT_*D_;
  const bf16* Vh = Vt + (size_t)h*D_*STOT_;

  bf16x8 qf[2][4];
  #pragma unroll
  for (int qt = 0; qt < 2; qt++)
    #pragma unroll
    for (int kk = 0; kk < 4; kk++)
      qf[qt][kk] = *(const bf16x8*)(Qh + (size_t)(qbase + qt*16 + lr)*D_ + kk*32 + lg*8);

  f32x4 acc[2][8] = {};
  float mrun[2] = {-3.0e38f, -3.0e38f}, lrun[2] = {0.f, 0.f};

  const int krow = t >> 4, kslot = t & 15;
  const int vrow = t >> 3, vslot = t & 7;

  auto STAGE = [&](int buf, int kv){
    #pragma unroll
    for (int i = 0; i < 4; i++){
      const int r = i*16 + krow;
      gll16(Kh + (size_t)(kv + r)*D_ + ((kslot ^ (r & 7))*8),
            (void*)(&Ks[buf][0] + (size_t)t*8 + i*2048));
    }
    #pragma unroll
    for (int i = 0; i < 4; i++){
      const int r = i*32 + vrow;
      gll16(Vh + (size_t)r*STOT_ + kv + ((vslot ^ (r & 7))*8),
            (void*)(&Vs[buf][0] + (size_t)t*8 + i*2048));
    }
  };

  STAGE(0, 0);
  __syncthreads();
  int cur = 0;
  for (int kv = 0; kv < STOT_; kv += 64){
    if (kv + 64 < STOT_) STAGE(cur ^ 1, kv + 64);

    f32x4 st[2][4] = {};
    #pragma unroll
    for (int tt = 0; tt < 4; tt++){
      const int kr = tt*16 + lr;
      #pragma unroll
      for (int kk = 0; kk < 4; kk++){
        const bf16x8 kf = *(const bf16x8*)(&Ks[cur][0] + kr*128 + (((kk*4 + lg) ^ (kr & 7))*8));
        st[0][tt] = __builtin_amdgcn_mfma_f32_16x16x32_bf16(kf, qf[0][kk], st[0][tt], 0, 0, 0);
        st[1][tt] = __builtin_amdgcn_mfma_f32_16x16x32_bf16(kf, qf[1][kk], st[1][tt], 0, 0, 0);
      }
    }
    #pragma unroll
    for (int qt = 0; qt < 2; qt++){
      const int q = qt*16 + lr;
      float sv[4][4];
      float vmax = -3.0e38f;
      #pragma unroll
      for (int tt = 0; tt < 4; tt++)
        #pragma unroll
        for (int r = 0; r < 4; r++){ const float x = st[qt][tt][r]*SCALE_; sv[tt][r] = x; vmax = fmaxf(vmax, x); }
      vmax = fmaxf(vmax, __shfl_xor(vmax, 16));
      vmax = fmaxf(vmax, __shfl_xor(vmax, 32));
      // T13 defer-max: skip O-rescale when tile max doesn't exceed running max + 8
      const bool grow = __any(vmax > mrun[qt] + 8.0f);
      float mnew = mrun[qt];
      if (grow){
        mnew = fmaxf(mrun[qt], vmax);
        const float alpha = __expf(mrun[qt] - mnew);
        lrun[qt] *= alpha;
        #pragma unroll
        for (int n = 0; n < 8; n++)
          #pragma unroll
          for (int r = 0; r < 4; r++) acc[qt][n][r] *= alpha;
        mrun[qt] = mnew;
      }
      float rs = 0.f;
      #pragma unroll
      for (int tt = 0; tt < 4; tt++){
        bf16x4 pq;
        #pragma unroll
        for (int r = 0; r < 4; r++){
          const float p = __expf(sv[tt][r] - mnew);
          rs += p;
          pq[r] = (bf16)p;
        }
        *(bf16x4*)(&plds[w][q*64 + (((tt*2 + (lg >> 1)) ^ (q & 7))*8) + (lg & 1)*4]) = pq;
      }
      rs += __shfl_xor(rs, 16);
      rs += __shfl_xor(rs, 32);
      lrun[qt] += rs;
    }
    #pragma unroll
    for (int ks = 0; ks < 2; ks++){
      const bf16x8 pb0 = *(const bf16x8*)(&plds[w][(lr)*64      + (((ks*4 + lg) ^ (lr & 7))*8)]);
      const bf16x8 pb1 = *(const bf16x8*)(&plds[w][(16 + lr)*64 + (((ks*4 + lg) ^ (lr & 7))*8)]);
      #pragma unroll
      for (int n = 0; n < 8; n++){
        const int vr = n*16 + lr;
        const bf16x8 vf = *(const bf16x8*)(&Vs[cur][0] + vr*64 + (((ks*4 + lg) ^ (vr & 7))*8));
        acc[0][n] = __builtin_amdgcn_mfma_f32_16x16x32_bf16(vf, pb0, acc[0][n], 0, 0, 0);
        acc[1][n] = __builtin_amdgcn_mfma_f32_16x16x32_bf16(vf, pb1, acc[1][n], 0, 0, 0);
      }
    }
    __syncthreads();
    cur ^= 1;
  }
  const bool hid = (qbase >= STXT_);
  #pragma unroll
  for (int qt = 0; qt < 2; qt++){
    const float inv = 1.0f/lrun[qt];
    const int row = qbase + qt*16 + lr;
    #pragma unroll
    for (int n = 0; n < 8; n++){
      const size_t cbase = (size_t)row*HID_ + h*D_ + n*16 + lg*4;
      if (hid){
        const bf16x4 ip = *(const bf16x4*)(ipOut + (size_t)(row - STXT_)*HID_ + h*D_ + n*16 + lg*4);
        bf16x4 o;
        #pragma unroll
        for (int r = 0; r < 4; r++) o[r] = (bf16)(acc[qt][n][r]*inv + (float)ip[r]);
        *(bf16x4*)(attnOut + cbase) = o;
      } else {
        bf16x4 o;
        #pragma unroll
        for (int r = 0; r < 4; r++) o[r] = (bf16)(acc[qt][n][r]*inv);
        *(bf16x4*)(attnOut + cbase) = o;
      }
    }
  }
}

extern "C" void kernel_launch(void* const* d_in, const int* in_sizes, int n_in,
                              void* d_out, int out_size, void* d_ws, size_t ws_size,
                              hipStream_t stream)
{
  const float* HS   = (const float*)d_in[0];
  const float* ENC  = (const float*)d_in[1];
  const float* IMG  = (const float*)d_in[2];
  const float* COS  = (const float*)d_in[3];
  const float* SIN  = (const float*)d_in[4];
  const float* Wq   = (const float*)d_in[5];  const float* bq  = (const float*)d_in[6];
  const float* Wk   = (const float*)d_in[7];  const float* bk  = (const float*)d_in[8];
  const float* Wv   = (const float*)d_in[9];  const float* bv  = (const float*)d_in[10];
  const float* Waq  = (const float*)d_in[11]; const float* baq = (const float*)d_in[12];
  const float* Wak  = (const float*)d_in[13]; const float* bak = (const float*)d_in[14];
  const float* Wav  = (const float*)d_in[15]; const float* bav = (const float*)d_in[16];
  const float* Wkip = (const float*)d_in[17]; const float* Wvip= (const float*)d_in[18];
  const float* Wo   = (const float*)d_in[19]; const float* bo  = (const float*)d_in[20];
  const float* Wao  = (const float*)d_in[21]; const float* bao = (const float*)d_in[22];

  char* wsb = (char*)d_ws;
  size_t off = 0;
  auto alloc = [&](size_t bytes) -> char* {
    char* p = wsb + off; off += (bytes + 255) & ~((size_t)255); return p;
  };
  bf16* rawQ   = (bf16*)alloc((size_t)SIMG_*HID_*2);
  bf16* rawK   = (bf16*)alloc((size_t)SIMG_*HID_*2);
  bf16* rawV   = (bf16*)alloc((size_t)SIMG_*HID_*2);
  bf16* rawEQ  = (bf16*)alloc((size_t)STXT_*HID_*2);
  bf16* rawEK  = (bf16*)alloc((size_t)STXT_*HID_*2);
  bf16* rawEV  = (bf16*)alloc((size_t)STXT_*HID_*2);
  bf16* Qb     = (bf16*)alloc((size_t)H_*STOT_*D_*2);
  bf16* Kb     = (bf16*)alloc((size_t)H_*STOT_*D_*2);
  bf16* Vtb    = (bf16*)alloc((size_t)H_*STOT_*D_*2);
  bf16* AOUT   = (bf16*)alloc((size_t)STOT_*HID_*2);
  bf16* IPOUT  = (bf16*)alloc((size_t)SIMG_*HID_*2);
  float* KIPF  = (float*)alloc((size_t)H_*4*D_*4);
  float* VIPF  = (float*)alloc((size_t)H_*4*D_*4);
  bf16* HSb    = (bf16*)alloc((size_t)SIMG_*HID_*2);
  bf16* ENCb   = (bf16*)alloc((size_t)STXT_*HID_*2);
  bf16* Wb8    = (bf16*)alloc((size_t)8*HH_*2);

  dim3 blk(256);
  dim3 blk512(512);
  // prep: ip projections first (long pole), then persistent grid-strided conversions
  k_prep<<<dim3(48 + CONV_BLK), blk, 0, stream>>>(HS, ENC, Wq, Wk, Wv, Waq, Wak, Wav, Wo, Wao,
                                                  IMG, Wkip, Wvip, HSb, ENCb, Wb8, KIPF, VIPF);
  // fused hid+enc QKV projections (8-wave pipelined, XCD-chunked)
  k_gemm8_qkv<<<dim3(720), blk512, 0, stream>>>(HSb, ENCb, Wb8,
                                                bq, bk, bv, baq, bak, bav,
                                                rawQ, rawK, rawV, rawEQ, rawEK, rawEV);
  // norm + rope (q,k) + fused ip attention (persistent grid-stride, no LDS)
  k_finish_qk2<<<dim3(FIN_BLK), blk, 0, stream>>>(rawQ, rawK, rawEQ, rawEK, COS, SIN,
                                                  KIPF, VIPF, Qb, Kb, IPOUT);
  // V transpose (own kernel: 33KB LDS stays isolated)
  k_vtrans<<<dim3(20,24), blk, 0, stream>>>(rawV, rawEV, Vtb);
  // main attention (+ fused ip add on hid rows, defer-max)
  k_flash3<<<dim3(480), blk, 0, stream>>>(Qb, Kb, Vtb, IPOUT, AOUT);
  // epilogue projections: hid rows of AOUT already include ip contribution
  float* outp = (float*)d_out;
  k_gemm8_out<<<dim3(240), blk512, 0, stream>>>(AOUT + (size_t)STXT_*HID_, AOUT, Wb8, bo, bao, outp);
}

// Round 15
// 512.238 us; speedup vs baseline: 1.0427x; 1.0427x over previous
//
#include <hip/hip_runtime.h>

typedef __bf16 bf16;
typedef __bf16 bf16x2 __attribute__((ext_vector_type(2)));
typedef __bf16 bf16x4 __attribute__((ext_vector_type(4)));
typedef __bf16 bf16x8 __attribute__((ext_vector_type(8)));
typedef float  f32x4  __attribute__((ext_vector_type(4)));

#define H_    24
#define D_    128
#define HID_  3072
#define SIMG_ 2048
#define STXT_ 512
#define STOT_ 2560
#define EPS_  1e-5f
#define SCALE_ 0.08838834764831845f   // 1/sqrt(128)
#define HH_   ((size_t)HID_*HID_)

// ---- async global->LDS, 16B per lane (wave-uniform dest base + lane*16)
typedef __attribute__((address_space(3))) unsigned int lds_uint;
typedef const __attribute__((address_space(1))) unsigned int glb_uint;
__device__ __forceinline__ void gll16(const void* g, void* l){
  __builtin_amdgcn_global_load_lds((glb_uint*)g, (lds_uint*)l, 16, 0, 0);
}

__device__ inline bf16x8 frag8f(const float* __restrict__ p){
  const f32x4 a = *(const f32x4*)p;
  const f32x4 b = *(const f32x4*)(p + 4);
  bf16x8 r;
  r[0]=(bf16)a[0]; r[1]=(bf16)a[1]; r[2]=(bf16)a[2]; r[3]=(bf16)a[3];
  r[4]=(bf16)b[0]; r[5]=(bf16)b[1]; r[6]=(bf16)b[2]; r[7]=(bf16)b[3];
  return r;
}

__device__ __forceinline__ void cvt8(const float* __restrict__ s, bf16* __restrict__ d, int i){
  const f32x4 a = *(const f32x4*)(s + i);
  const f32x4 b = *(const f32x4*)(s + i + 4);
  bf16x8 o;
  o[0]=(bf16)a[0]; o[1]=(bf16)a[1]; o[2]=(bf16)a[2]; o[3]=(bf16)a[3];
  o[4]=(bf16)b[0]; o[5]=(bf16)b[1]; o[6]=(bf16)b[2]; o[7]=(bf16)b[3];
  *(bf16x8*)(d + i) = o;
}

// ================= k_prep: 48 ip-gemm blocks first + 2048 persistent grid-strided
// conversion blocks (r11-proven).
#define CONV_BLK 2048
__global__ __launch_bounds__(256) void k_prep(
    const float* __restrict__ HS, const float* __restrict__ ENC,
    const float* __restrict__ W0, const float* __restrict__ W1,
    const float* __restrict__ W2, const float* __restrict__ W3,
    const float* __restrict__ W4, const float* __restrict__ W5,
    const float* __restrict__ W6, const float* __restrict__ W7,
    const float* __restrict__ IMG,
    const float* __restrict__ Wkip, const float* __restrict__ Wvip,
    bf16* __restrict__ HSb, bf16* __restrict__ ENCb, bf16* __restrict__ Wb8,
    float* __restrict__ Kip, float* __restrict__ Vip)
{
  __shared__ float tile[4][128];
  const int bx = (int)blockIdx.x;
  const int t = (int)threadIdx.x;
  if (bx < 48){
    const bool isV = (bx >= 24);
    const int h = bx % 24;
    const float* Wm = isV ? Wvip : Wkip;
    const int w = t >> 6, l = t & 63;
    const int lr = l & 15, lg = l >> 4;
    const int col0 = h*128 + w*32;
    f32x4 acc0 = {}, acc1 = {};
    const float* arow = IMG + (size_t)((lr < 4) ? lr : 0)*HID_;
    const float* wr0 = Wm + (size_t)(col0 + lr)*HID_;
    const float* wr1 = Wm + (size_t)(col0 + 16 + lr)*HID_;
    for (int k0 = 0; k0 < HID_; k0 += 32){
      const bf16x8 af = frag8f(arow + k0 + lg*8);
      acc0 = __builtin_amdgcn_mfma_f32_16x16x32_bf16(af, frag8f(wr0 + k0 + lg*8), acc0, 0, 0, 0);
      acc1 = __builtin_amdgcn_mfma_f32_16x16x32_bf16(af, frag8f(wr1 + k0 + lg*8), acc1, 0, 0, 0);
    }
    if (lg == 0){
      #pragma unroll
      for (int r = 0; r < 4; r++){
        tile[r][w*32 + lr]      = acc0[r];
        tile[r][w*32 + 16 + lr] = acc1[r];
      }
    }
    __syncthreads();
    if (isV){
      const int e = t*2;
      const int j = e >> 7, d = e & 127;
      Vip[(size_t)(h*4 + j)*D_ + d]     = tile[j][d];
      Vip[(size_t)(h*4 + j)*D_ + d + 1] = tile[j][d + 1];
    } else {
      const float v0 = tile[w][2*l], v1 = tile[w][2*l + 1];
      float ss = v0*v0 + v1*v1;
      #pragma unroll
      for (int m = 1; m < 64; m <<= 1) ss += __shfl_xor(ss, m);
      const float rk = rsqrtf(ss*(1.0f/128.0f) + EPS_);
      Kip[(size_t)(h*4 + w)*D_ + 2*l]     = v0*rk;
      Kip[(size_t)(h*4 + w)*D_ + 2*l + 1] = v1*rk;
    }
  } else {
    for (int c = bx - 48; c < 20352; c += CONV_BLK){
      const float* s; bf16* d; int base;
      if (c < 1536){ s = HS;  d = HSb;  base = c*4096; }
      else if (c < 1920){ s = ENC; d = ENCb; base = (c - 1536)*4096; }
      else {
        const int idx = c - 1920;
        const int wi = idx / 2304;
        s = (wi==0)?W0:(wi==1)?W1:(wi==2)?W2:(wi==3)?W3:(wi==4)?W4:(wi==5)?W5:(wi==6)?W6:W7;
        d = Wb8 + (size_t)wi*HH_;
        base = (idx % 2304)*4096;
      }
      const int i = base + t*16;
      cvt8(s, d, i);
      cvt8(s, d, i + 8);
    }
  }
}

#define MFMA_ __builtin_amdgcn_mfma_f32_16x16x32_bf16
#define WAIT6  asm volatile("s_waitcnt vmcnt(6)" ::: "memory")
#define WAIT5  asm volatile("s_waitcnt vmcnt(5)" ::: "memory")
#define WAIT0  asm volatile("s_waitcnt vmcnt(0)" ::: "memory")
#define NOWAIT (void)0

// ================= k_gemm192_qkv: BM=128 x BN=192, 4 waves (2x2, wave 64x96), BK=32,
// triple-buffered counted-vmcnt (5 loads/tile, distance 2, WAIT5). LDS 60KB -> 2 blk/CU
// (8 waves/CU, same as r6 core). reads/MFMA = 10/24 = 0.417 -> LDS-BW ceiling ~36%
// (r6 core: 0.5 -> 30%, measured exactly 30%). Grid 960 = 1.875 rounds @2/CU = 93.75%.
// Layout: r12-verified 2-rows-per-128B-line XOR granule swizzle (0 conflicts).
__global__ __launch_bounds__(256, 2) void k_gemm192_qkv(
    const bf16* __restrict__ Ahid, const bf16* __restrict__ Aenc,
    const bf16* __restrict__ Wb,
    const float* bq, const float* bk, const float* bv,
    const float* baq, const float* bak, const float* bav,
    bf16* Cq, bf16* Ck, bf16* Cv, bf16* Ceq, bf16* Cek, bf16* Cev)
{
  __shared__ __align__(16) bf16 Al[3][4096];   // 128 rows x 32
  __shared__ __align__(16) bf16 Bl[3][6144];   // 192 rows x 32
  const int t = (int)threadIdx.x;
  const int w = t >> 6, l = t & 63;
  const int lr = l & 15, lg = l >> 4;
  const int wr = w >> 1, wc = w & 1;

  const int lin = (int)blockIdx.x;
  const int work = (lin & 7)*120 + (lin >> 3);
  const int mt = work / 48;
  const int ct = work % 48;
  const int which = ct % 3;
  const int nb = (ct/3)*192;
  const int enc = (mt >= 16) ? 1 : 0;
  const int mb = (enc ? (mt - 16) : mt)*128;
  const bf16* A = enc ? Aenc : Ahid;
  const int widx = which + enc*3;
  const bf16* W = Wb + (size_t)widx*HH_;
  const float* bias = (which==0) ? (enc?baq:bq) : (which==1) ? (enc?bak:bk) : (enc?bav:bv);
  bf16* Cm = (which==0) ? (enc?Ceq:Cq) : (which==1) ? (enc?Cek:Ck) : (enc?Cev:Cv);

  // staging decode: granule gd -> line l = gd>>3, logical u = (gd&7)^(l&7),
  // row = 2l + (u>>2), kcols (u&3)*8..+8. A granules {t, t+256}; B {t, t+256, t+512}.
  const int lA0 = t >> 3,          uA0 = (t & 7) ^ (lA0 & 7);
  const int gA1 = t + 256, lA1 = gA1 >> 3, uA1 = (gA1 & 7) ^ (lA1 & 7);
  const bf16* Asrc0 = A + (size_t)(mb + 2*lA0 + (uA0 >> 2))*HID_ + (uA0 & 3)*8;
  const bf16* Asrc1 = A + (size_t)(mb + 2*lA1 + (uA1 >> 2))*HID_ + (uA1 & 3)*8;
  const int lB0 = t >> 3,          uB0 = (t & 7) ^ (lB0 & 7);
  const int gB1 = t + 256, lB1 = gB1 >> 3, uB1 = (gB1 & 7) ^ (lB1 & 7);
  const int gB2 = t + 512, lB2 = gB2 >> 3, uB2 = (gB2 & 7) ^ (lB2 & 7);
  const bf16* Bsrc0 = W + (size_t)(nb + 2*lB0 + (uB0 >> 2))*HID_ + (uB0 & 3)*8;
  const bf16* Bsrc1 = W + (size_t)(nb + 2*lB1 + (uB1 >> 2))*HID_ + (uB1 & 3)*8;
  const bf16* Bsrc2 = W + (size_t)(nb + 2*lB2 + (uB2 >> 2))*HID_ + (uB2 & 3)*8;

#define SA192(buf, TT) { gll16(Asrc0 + (TT)*32, &Al[buf][0] + t*8); \
                         gll16(Asrc1 + (TT)*32, &Al[buf][0] + 2048 + t*8); }
#define SB192(buf, TT) { gll16(Bsrc0 + (TT)*32, &Bl[buf][0] + t*8); \
                         gll16(Bsrc1 + (TT)*32, &Bl[buf][0] + 2048 + t*8); \
                         gll16(Bsrc2 + (TT)*32, &Bl[buf][0] + 4096 + t*8); }

  // frag read offsets (elements): row = base + lr -> line = base/2 + (lr>>1)
  const int gx = ((((lr & 1) << 2) | lg) ^ ((lr >> 1) & 7)) * 8;
  const int baseA = (wr*32 + (lr >> 1))*64 + gx;   // + m*512
  const int baseB = (wc*48 + (lr >> 1))*64 + gx;   // + n*512

  f32x4 acc[4][6] = {};

#define MMB(bb, n) \
    acc[0][n]=MFMA_(a0,bb,acc[0][n],0,0,0); acc[1][n]=MFMA_(a1,bb,acc[1][n],0,0,0); \
    acc[2][n]=MFMA_(a2,bb,acc[2][n],0,0,0); acc[3][n]=MFMA_(a3,bb,acc[3][n],0,0,0);

#define TILE192(C, NXT, TT, PRE, TW)                                         \
  {                                                                          \
    bf16x8 a0,a1,a2,a3,b0,b1,b2;                                             \
    a0 = *(const bf16x8*)(&Al[C][0] + baseA);                                \
    a1 = *(const bf16x8*)(&Al[C][0] + baseA + 512);                          \
    a2 = *(const bf16x8*)(&Al[C][0] + baseA + 1024);                         \
    a3 = *(const bf16x8*)(&Al[C][0] + baseA + 1536);                         \
    b0 = *(const bf16x8*)(&Bl[C][0] + baseB);                                \
    b1 = *(const bf16x8*)(&Bl[C][0] + baseB + 512);                          \
    b2 = *(const bf16x8*)(&Bl[C][0] + baseB + 1024);                         \
    if (PRE){ SA192(NXT, (TT)+2); }                                          \
    __builtin_amdgcn_s_setprio(1);                                           \
    MMB(b0,0) MMB(b1,1) MMB(b2,2)                                            \
    __builtin_amdgcn_s_setprio(0);                                           \
    b0 = *(const bf16x8*)(&Bl[C][0] + baseB + 1536);                         \
    b1 = *(const bf16x8*)(&Bl[C][0] + baseB + 2048);                         \
    b2 = *(const bf16x8*)(&Bl[C][0] + baseB + 2560);                         \
    if (PRE){ SB192(NXT, (TT)+2); }                                          \
    __builtin_amdgcn_s_setprio(1);                                           \
    MMB(b0,3) MMB(b1,4) MMB(b2,5)                                            \
    __builtin_amdgcn_s_setprio(0);                                           \
    TW;                                                                      \
    __builtin_amdgcn_s_barrier();                                            \
  }

  // prologue: tile 0 -> buf0, tile 1 -> buf1 (10 loads); WAIT5 -> tile0 resident
  SA192(0,0); SB192(0,0);
  SA192(1,1); SB192(1,1);
  WAIT5;
  __builtin_amdgcn_s_barrier();

  // 96 K-tiles of 32: loop tiles 0..92, peeled 93/94/95
  for (int base = 0; base < 93; base += 3){
    TILE192(0, 2, base,   true, WAIT5);
    TILE192(1, 0, base+1, true, WAIT5);
    TILE192(2, 1, base+2, true, WAIT5);
  }
  TILE192(0, 2, 93, true,  WAIT5);   // stages tile 95; end-wait: tile 94 resident
  TILE192(1, 0, 94, false, WAIT0);   // end-wait: tile 95 resident
  TILE192(2, 1, 95, false, NOWAIT);
#undef TILE192
#undef MMB
#undef SA192
#undef SB192

  #pragma unroll
  for (int n = 0; n < 6; n++){
    const int col = nb + wc*96 + n*16 + lr;
    const float bvl = bias[col];
    #pragma unroll
    for (int m = 0; m < 4; m++){
      #pragma unroll
      for (int r = 0; r < 4; r++){
        const int row = mb + wr*64 + m*16 + lg*4 + r;
        Cm[(size_t)row*HID_ + col] = (bf16)(acc[m][n][r] + bvl);
      }
    }
  }
}

// ================= 8-wave, BM=128 x BN=256, BK=64, triple-buffered counted-vmcnt
// pipeline (r6-proven). Used for the output GEMM (240 blocks, 93.75% grid fit).
#define MM(bfr, n) \
    acc[0][n]=MFMA_(af0,bfr,acc[0][n],0,0,0); acc[1][n]=MFMA_(af1,bfr,acc[1][n],0,0,0); \
    acc[2][n]=MFMA_(af2,bfr,acc[2][n],0,0,0); acc[3][n]=MFMA_(af3,bfr,acc[3][n],0,0,0);

__device__ __forceinline__ void gemm8_core(
    const bf16* __restrict__ A, const bf16* __restrict__ W,
    int mb, int nb,
    f32x4 (&acc)[4][4],
    bf16 (&Al)[3][128][64],
    bf16 (&Bl)[3][256][64])
{
  const int t = (int)threadIdx.x;
  const int w = t >> 6, l = t & 63;
  const int lr = l & 15, lg = l >> 4;
  const int wr = w >> 2, wc = w & 3;
  const int srow = t >> 3;
  const int soff = ((t & 7) ^ (srow & 7)) * 8;

  const bf16* Abase = A + (size_t)(mb + srow)*HID_ + soff;
  const bf16* Wbase = W + (size_t)(nb + srow)*HID_ + soff;

#define SA(buf, tt, i) gll16(Abase + (size_t)(i)*64*HID_ + (tt)*64, &Al[buf][0][0] + (i)*4096 + t*8)
#define SB(buf, tt, i) gll16(Wbase + (size_t)(i)*64*HID_ + (tt)*64, &Bl[buf][0][0] + (i)*4096 + t*8)

  const int arow_ = wr*64 + lr;
  const int brow_ = wc*64 + lr;
  const int sx = lr & 7;

  SA(0,0,0); SA(0,0,1); SB(0,0,0); SB(0,0,1); SB(0,0,2); SB(0,0,3);
  SA(1,1,0); SA(1,1,1); SB(1,1,0); SB(1,1,1); SB(1,1,2); SB(1,1,3);
  WAIT6;
  __builtin_amdgcn_s_barrier();

#define TILE(C, NXT, TT, PRE, TW)                                            \
  {                                                                          \
    const int s0_ = (lg^sx)*8, s1_ = ((4+lg)^sx)*8;                          \
    bf16x8 af0,af1,af2,af3,b0,b1;                                            \
    af0=*(const bf16x8*)&Al[C][arow_   ][s0_];                               \
    af1=*(const bf16x8*)&Al[C][arow_+16][s0_];                               \
    af2=*(const bf16x8*)&Al[C][arow_+32][s0_];                               \
    af3=*(const bf16x8*)&Al[C][arow_+48][s0_];                               \
    b0 =*(const bf16x8*)&Bl[C][brow_   ][s0_];                               \
    b1 =*(const bf16x8*)&Bl[C][brow_+16][s0_];                               \
    if (PRE){ SA(NXT,(TT)+2,0); SA(NXT,(TT)+2,1); }                          \
    __builtin_amdgcn_s_setprio(1); MM(b0,0) MM(b1,1)                         \
    __builtin_amdgcn_s_setprio(0);                                           \
    b0 =*(const bf16x8*)&Bl[C][brow_+32][s0_];                               \
    b1 =*(const bf16x8*)&Bl[C][brow_+48][s0_];                               \
    if (PRE){ SB(NXT,(TT)+2,0); SB(NXT,(TT)+2,1); }                          \
    __builtin_amdgcn_s_setprio(1); MM(b0,2) MM(b1,3)                         \
    __builtin_amdgcn_s_setprio(0);                                           \
    af0=*(const bf16x8*)&Al[C][arow_   ][s1_];                               \
    af1=*(const bf16x8*)&Al[C][arow_+16][s1_];                               \
    af2=*(const bf16x8*)&Al[C][arow_+32][s1_];                               \
    af3=*(const bf16x8*)&Al[C][arow_+48][s1_];                               \
    b0 =*(const bf16x8*)&Bl[C][brow_   ][s1_];                               \
    b1 =*(const bf16x8*)&Bl[C][brow_+16][s1_];                               \
    if (PRE){ SB(NXT,(TT)+2,2); SB(NXT,(TT)+2,3); }                          \
    __builtin_amdgcn_s_setprio(1); MM(b0,0) MM(b1,1)                         \
    __builtin_amdgcn_s_setprio(0);                                           \
    b0 =*(const bf16x8*)&Bl[C][brow_+32][s1_];                               \
    b1 =*(const bf16x8*)&Bl[C][brow_+48][s1_];                               \
    __builtin_amdgcn_s_setprio(1); MM(b0,2) MM(b1,3)                         \
    __builtin_amdgcn_s_setprio(0);                                           \
    TW;                                                                      \
    __builtin_amdgcn_s_barrier();                                            \
  }

  for (int base = 0; base < 45; base += 3){
    TILE(0, 2, base,   true, WAIT6);
    TILE(1, 0, base+1, true, WAIT6);
    TILE(2, 1, base+2, true, WAIT6);
  }
  TILE(0, 2, 45, true,  WAIT6);
  TILE(1, 0, 46, false, WAIT0);
  TILE(2, 1, 47, false, NOWAIT);
#undef TILE
#undef SA
#undef SB
}

// ---------------- Output instantiation: grid 240 (1-D). fp32 out.
__global__ __launch_bounds__(512, 1) void k_gemm8_out(
    const bf16* __restrict__ Ahid, const bf16* __restrict__ Aenc,
    const bf16* __restrict__ Wb,
    const float* bo, const float* bao, float* __restrict__ outp)
{
  __shared__ __align__(16) bf16 Al[3][128][64];
  __shared__ __align__(16) bf16 Bl[3][256][64];
  const int lin = (int)blockIdx.x;
  const int work = (lin & 7)*30 + (lin >> 3);
  const int mt = work / 12;
  const int nb = (work % 12)*256;
  const int enc = (mt >= 16) ? 1 : 0;
  const int mb = (enc ? (mt - 16) : mt)*128;
  const bf16* A = enc ? Aenc : Ahid;
  const bf16* W = Wb + (size_t)(enc ? 7 : 6)*HH_;
  const float* bias = enc ? bao : bo;
  float* C = outp + (enc ? (size_t)SIMG_*HID_ : 0);

  f32x4 acc[4][4] = {};
  gemm8_core(A, W, mb, nb, acc, Al, Bl);

  const int w = (int)(threadIdx.x >> 6), l = (int)(threadIdx.x & 63u);
  const int lr = l & 15, lg = l >> 4;
  const int wr = w >> 2, wc = w & 3;
  #pragma unroll
  for (int nf = 0; nf < 4; nf++){
    const int col = nb + wc*64 + nf*16 + lr;
    const float bvl = bias[col];
    #pragma unroll
    for (int m = 0; m < 4; m++){
      #pragma unroll
      for (int r = 0; r < 4; r++){
        const int row = mb + wr*64 + m*16 + lg*4 + r;
        C[(size_t)row*HID_ + col] = acc[m][nf][r] + bvl;
      }
    }
  }
}

// ================= k_finish_qk2: persistent grid-strided (2048 blocks).
// RMSNorm + RoPE for q,k; fused ip-attention on hid rows. No LDS.
#define FIN_BLK 2048
__global__ __launch_bounds__(256) void k_finish_qk2(
    const bf16* __restrict__ rawQ, const bf16* __restrict__ rawK,
    const bf16* __restrict__ rawEQ, const bf16* __restrict__ rawEK,
    const float* __restrict__ cosT, const float* __restrict__ sinT,
    const float* __restrict__ Kip, const float* __restrict__ Vip,
    bf16* __restrict__ Qh, bf16* __restrict__ Kh, bf16* __restrict__ ipOut)
{
  const int wv = (int)(threadIdx.x >> 6);
  const int l = (int)(threadIdx.x & 63u);
  const int d0 = 2*l, d1 = 2*l + 1;
  for (int b = (int)blockIdx.x; b < 15360; b += FIN_BLK){
    const int wid = b*4 + wv;
    const int s = wid / H_;
    const int h = wid % H_;
    const bf16 *sq_, *sk_;
    if (s < STXT_){
      const size_t off = (size_t)s*HID_ + h*D_;
      sq_ = rawEQ + off; sk_ = rawEK + off;
    } else {
      const size_t off = (size_t)(s - STXT_)*HID_ + h*D_;
      sq_ = rawQ + off; sk_ = rawK + off;
    }
    float q0 = sq_[d0], q1 = sq_[d1];
    float k0 = sk_[d0], k1 = sk_[d1];
    float ssq = q0*q0 + q1*q1;
    float ssk = k0*k0 + k1*k1;
    #pragma unroll
    for (int m = 1; m < 64; m <<= 1){ ssq += __shfl_xor(ssq, m); ssk += __shfl_xor(ssk, m); }
    const float rq = rsqrtf(ssq*(1.0f/128.0f) + EPS_);
    const float rk = rsqrtf(ssk*(1.0f/128.0f) + EPS_);
    q0 *= rq; q1 *= rq; k0 *= rk; k1 *= rk;
    const float c0 = cosT[(size_t)s*D_ + d0], c1 = cosT[(size_t)s*D_ + d1];
    const float s0 = sinT[(size_t)s*D_ + d0], s1 = sinT[(size_t)s*D_ + d1];
    const float qo0 = q0*c0 - q1*s0, qo1 = q1*c1 + q0*s1;
    const float ko0 = k0*c0 - k1*s0, ko1 = k1*c1 + k0*s1;
    const size_t qoff = ((size_t)h*STOT_ + s)*D_ + d0;
    Qh[qoff] = (bf16)qo0; Qh[qoff + 1] = (bf16)qo1;
    Kh[qoff] = (bf16)ko0; Kh[qoff + 1] = (bf16)ko1;

    if (s >= STXT_){
      const float* kb = Kip + (size_t)h*4*D_;
      const float* vb = Vip + (size_t)h*4*D_;
      float sc[4];
      #pragma unroll
      for (int j = 0; j < 4; j++) sc[j] = q0*kb[j*D_ + d0] + q1*kb[j*D_ + d1];
      #pragma unroll
      for (int m = 1; m < 64; m <<= 1){
        #pragma unroll
        for (int j = 0; j < 4; j++) sc[j] += __shfl_xor(sc[j], m);
      }
      const float mx = fmaxf(fmaxf(sc[0], sc[1]), fmaxf(sc[2], sc[3]));
      float p[4], ps = 0.f;
      #pragma unroll
      for (int j = 0; j < 4; j++){ p[j] = __expf((sc[j] - mx)*SCALE_); ps += p[j]; }
      const float inv = 1.0f/ps;
      float o0 = 0.f, o1 = 0.f;
      #pragma unroll
      for (int j = 0; j < 4; j++){ o0 += p[j]*vb[j*D_ + d0]; o1 += p[j]*vb[j*D_ + d1]; }
      const size_t dst = (size_t)(s - STXT_)*HID_ + h*D_;
      ipOut[dst + d0] = (bf16)(o0*inv);
      ipOut[dst + d1] = (bf16)(o1*inv);
    }
  }
}

// ---------------- V transpose: raw[E]V [s][h*128+d] -> Vt[h][d][s], LDS tiled.
__global__ __launch_bounds__(256) void k_vtrans(
    const bf16* __restrict__ rawV, const bf16* __restrict__ rawEV,
    bf16* __restrict__ Vt)
{
  __shared__ bf16 lt[128*130];
  const int t = (int)threadIdx.x;
  const int stile = (int)blockIdx.x*128;
  const int h = (int)blockIdx.y;
  #pragma unroll
  for (int i = 0; i < 8; i++){
    const int sl = i*16 + (t >> 4);
    const int s = stile + sl;
    const bf16* src = (s < STXT_) ? (rawEV + (size_t)s*HID_) : (rawV + (size_t)(s - STXT_)*HID_);
    const bf16x8 v = *(const bf16x8*)(src + h*D_ + (t & 15)*8);
    #pragma unroll
    for (int j = 0; j < 8; j++) lt[((t & 15)*8 + j)*130 + sl] = v[j];
  }
  __syncthreads();
  #pragma unroll
  for (int j = 0; j < 4; j++){
    const int d = j*32 + (t >> 3);
    const int s0 = (t & 7)*16;
    bf16x8 a, b;
    #pragma unroll
    for (int k = 0; k < 4; k++){
      const bf16x2 p = *(const bf16x2*)(lt + d*130 + s0 + 2*k);
      a[2*k] = p[0]; a[2*k+1] = p[1];
    }
    #pragma unroll
    for (int k = 0; k < 4; k++){
      const bf16x2 p = *(const bf16x2*)(lt + d*130 + s0 + 8 + 2*k);
      b[2*k] = p[0]; b[2*k+1] = p[1];
    }
    bf16* dst = Vt + ((size_t)h*D_ + d)*STOT_ + stile + s0;
    *(bf16x8*)dst = a;
    *(bf16x8*)(dst + 8) = b;
  }
}

// ---------------- Flash attention v3 + fused ip add + T13 defer-max. Grid 480 1-D.
__global__ __launch_bounds__(256, 2) void k_flash3(
    const bf16* __restrict__ Q, const bf16* __restrict__ K,
    const bf16* __restrict__ Vt, const bf16* __restrict__ ipOut,
    bf16* __restrict__ attnOut)
{
  __shared__ __align__(16) bf16 Ks[2][64*128];
  __shared__ __align__(16) bf16 Vs[2][128*64];
  __shared__ __align__(16) bf16 plds[4][32*64];
  const int t = (int)threadIdx.x;
  const int w = t >> 6, l = t & 63;
  const int lr = l & 15, lg = l >> 4;
  const int lin = (int)blockIdx.x;
  const int work = (lin & 7)*60 + (lin >> 3);
  const int h = work / 20;
  const int qbase = (work % 20)*128 + w*32;
  const bf16* Qh = Q  + (size_t)h*STOT_*D_;
  const bf16* Kh = K  + (size_t)h*STOT_*D_;
  const bf16* Vh = Vt + (size_t)h*D_*STOT_;

  bf16x8 qf[2][4];
  #pragma unroll
  for (int qt = 0; qt < 2; qt++)
    #pragma unroll
    for (int kk = 0; kk < 4; kk++)
      qf[qt][kk] = *(const bf16x8*)(Qh + (size_t)(qbase + qt*16 + lr)*D_ + kk*32 + lg*8);

  f32x4 acc[2][8] = {};
  float mrun[2] = {-3.0e38f, -3.0e38f}, lrun[2] = {0.f, 0.f};

  const int krow = t >> 4, kslot = t & 15;
  const int vrow = t >> 3, vslot = t & 7;

  auto STAGE = [&](int buf, int kv){
    #pragma unroll
    for (int i = 0; i < 4; i++){
      const int r = i*16 + krow;
      gll16(Kh + (size_t)(kv + r)*D_ + ((kslot ^ (r & 7))*8),
            (void*)(&Ks[buf][0] + (size_t)t*8 + i*2048));
    }
    #pragma unroll
    for (int i = 0; i < 4; i++){
      const int r = i*32 + vrow;
      gll16(Vh + (size_t)r*STOT_ + kv + ((vslot ^ (r & 7))*8),
            (void*)(&Vs[buf][0] + (size_t)t*8 + i*2048));
    }
  };

  STAGE(0, 0);
  __syncthreads();
  int cur = 0;
  for (int kv = 0; kv < STOT_; kv += 64){
    if (kv + 64 < STOT_) STAGE(cur ^ 1, kv + 64);

    f32x4 st[2][4] = {};
    #pragma unroll
    for (int tt = 0; tt < 4; tt++){
      const int kr = tt*16 + lr;
      #pragma unroll
      for (int kk = 0; kk < 4; kk++){
        const bf16x8 kf = *(const bf16x8*)(&Ks[cur][0] + kr*128 + (((kk*4 + lg) ^ (kr & 7))*8));
        st[0][tt] = __builtin_amdgcn_mfma_f32_16x16x32_bf16(kf, qf[0][kk], st[0][tt], 0, 0, 0);
        st[1][tt] = __builtin_amdgcn_mfma_f32_16x16x32_bf16(kf, qf[1][kk], st[1][tt], 0, 0, 0);
      }
    }
    #pragma unroll
    for (int qt = 0; qt < 2; qt++){
      const int q = qt*16 + lr;
      float sv[4][4];
      float vmax = -3.0e38f;
      #pragma unroll
      for (int tt = 0; tt < 4; tt++)
        #pragma unroll
        for (int r = 0; r < 4; r++){ const float x = st[qt][tt][r]*SCALE_; sv[tt][r] = x; vmax = fmaxf(vmax, x); }
      vmax = fmaxf(vmax, __shfl_xor(vmax, 16));
      vmax = fmaxf(vmax, __shfl_xor(vmax, 32));
      const bool grow = __any(vmax > mrun[qt] + 8.0f);
      float mnew = mrun[qt];
      if (grow){
        mnew = fmaxf(mrun[qt], vmax);
        const float alpha = __expf(mrun[qt] - mnew);
        lrun[qt] *= alpha;
        #pragma unroll
        for (int n = 0; n < 8; n++)
          #pragma unroll
          for (int r = 0; r < 4; r++) acc[qt][n][r] *= alpha;
        mrun[qt] = mnew;
      }
      float rs = 0.f;
      #pragma unroll
      for (int tt = 0; tt < 4; tt++){
        bf16x4 pq;
        #pragma unroll
        for (int r = 0; r < 4; r++){
          const float p = __expf(sv[tt][r] - mnew);
          rs += p;
          pq[r] = (bf16)p;
        }
        *(bf16x4*)(&plds[w][q*64 + (((tt*2 + (lg >> 1)) ^ (q & 7))*8) + (lg & 1)*4]) = pq;
      }
      rs += __shfl_xor(rs, 16);
      rs += __shfl_xor(rs, 32);
      lrun[qt] += rs;
    }
    #pragma unroll
    for (int ks = 0; ks < 2; ks++){
      const bf16x8 pb0 = *(const bf16x8*)(&plds[w][(lr)*64      + (((ks*4 + lg) ^ (lr & 7))*8)]);
      const bf16x8 pb1 = *(const bf16x8*)(&plds[w][(16 + lr)*64 + (((ks*4 + lg) ^ (lr & 7))*8)]);
      #pragma unroll
      for (int n = 0; n < 8; n++){
        const int vr = n*16 + lr;
        const bf16x8 vf = *(const bf16x8*)(&Vs[cur][0] + vr*64 + (((ks*4 + lg) ^ (vr & 7))*8));
        acc[0][n] = __builtin_amdgcn_mfma_f32_16x16x32_bf16(vf, pb0, acc[0][n], 0, 0, 0);
        acc[1][n] = __builtin_amdgcn_mfma_f32_16x16x32_bf16(vf, pb1, acc[1][n], 0, 0, 0);
      }
    }
    __syncthreads();
    cur ^= 1;
  }
  const bool hid = (qbase >= STXT_);
  #pragma unroll
  for (int qt = 0; qt < 2; qt++){
    const float inv = 1.0f/lrun[qt];
    const int row = qbase + qt*16 + lr;
    #pragma unroll
    for (int n = 0; n < 8; n++){
      const size_t cbase = (size_t)row*HID_ + h*D_ + n*16 + lg*4;
      if (hid){
        const bf16x4 ip = *(const bf16x4*)(ipOut + (size_t)(row - STXT_)*HID_ + h*D_ + n*16 + lg*4);
        bf16x4 o;
        #pragma unroll
        for (int r = 0; r < 4; r++) o[r] = (bf16)(acc[qt][n][r]*inv + (float)ip[r]);
        *(bf16x4*)(attnOut + cbase) = o;
      } else {
        bf16x4 o;
        #pragma unroll
        for (int r = 0; r < 4; r++) o[r] = (bf16)(acc[qt][n][r]*inv);
        *(bf16x4*)(attnOut + cbase) = o;
      }
    }
  }
}

extern "C" void kernel_launch(void* const* d_in, const int* in_sizes, int n_in,
                              void* d_out, int out_size, void* d_ws, size_t ws_size,
                              hipStream_t stream)
{
  const float* HS   = (const float*)d_in[0];
  const float* ENC  = (const float*)d_in[1];
  const float* IMG  = (const float*)d_in[2];
  const float* COS  = (const float*)d_in[3];
  const float* SIN  = (const float*)d_in[4];
  const float* Wq   = (const float*)d_in[5];  const float* bq  = (const float*)d_in[6];
  const float* Wk   = (const float*)d_in[7];  const float* bk  = (const float*)d_in[8];
  const float* Wv   = (const float*)d_in[9];  const float* bv  = (const float*)d_in[10];
  const float* Waq  = (const float*)d_in[11]; const float* baq = (const float*)d_in[12];
  const float* Wak  = (const float*)d_in[13]; const float* bak = (const float*)d_in[14];
  const float* Wav  = (const float*)d_in[15]; const float* bav = (const float*)d_in[16];
  const float* Wkip = (const float*)d_in[17]; const float* Wvip= (const float*)d_in[18];
  const float* Wo   = (const float*)d_in[19]; const float* bo  = (const float*)d_in[20];
  const float* Wao  = (const float*)d_in[21]; const float* bao = (const float*)d_in[22];

  char* wsb = (char*)d_ws;
  size_t off = 0;
  auto alloc = [&](size_t bytes) -> char* {
    char* p = wsb + off; off += (bytes + 255) & ~((size_t)255); return p;
  };
  bf16* rawQ   = (bf16*)alloc((size_t)SIMG_*HID_*2);
  bf16* rawK   = (bf16*)alloc((size_t)SIMG_*HID_*2);
  bf16* rawV   = (bf16*)alloc((size_t)SIMG_*HID_*2);
  bf16* rawEQ  = (bf16*)alloc((size_t)STXT_*HID_*2);
  bf16* rawEK  = (bf16*)alloc((size_t)STXT_*HID_*2);
  bf16* rawEV  = (bf16*)alloc((size_t)STXT_*HID_*2);
  bf16* Qb     = (bf16*)alloc((size_t)H_*STOT_*D_*2);
  bf16* Kb     = (bf16*)alloc((size_t)H_*STOT_*D_*2);
  bf16* Vtb    = (bf16*)alloc((size_t)H_*STOT_*D_*2);
  bf16* AOUT   = (bf16*)alloc((size_t)STOT_*HID_*2);
  bf16* IPOUT  = (bf16*)alloc((size_t)SIMG_*HID_*2);
  float* KIPF  = (float*)alloc((size_t)H_*4*D_*4);
  float* VIPF  = (float*)alloc((size_t)H_*4*D_*4);
  bf16* HSb    = (bf16*)alloc((size_t)SIMG_*HID_*2);
  bf16* ENCb   = (bf16*)alloc((size_t)STXT_*HID_*2);
  bf16* Wb8    = (bf16*)alloc((size_t)8*HH_*2);

  dim3 blk(256);
  dim3 blk512(512);
  // prep: ip projections first (long pole), then persistent grid-strided conversions
  k_prep<<<dim3(48 + CONV_BLK), blk, 0, stream>>>(HS, ENC, Wq, Wk, Wv, Waq, Wak, Wav, Wo, Wao,
                                                  IMG, Wkip, Wvip, HSb, ENCb, Wb8, KIPF, VIPF);
  // fused hid+enc QKV projections (128x192 tile, 2 blocks/CU, grid 960 = 93.75% util)
  k_gemm192_qkv<<<dim3(960), blk, 0, stream>>>(HSb, ENCb, Wb8,
                                               bq, bk, bv, baq, bak, bav,
                                               rawQ, rawK, rawV, rawEQ, rawEK, rawEV);
  // norm + rope (q,k) + fused ip attention (persistent grid-stride, no LDS)
  k_finish_qk2<<<dim3(FIN_BLK), blk, 0, stream>>>(rawQ, rawK, rawEQ, rawEK, COS, SIN,
                                                  KIPF, VIPF, Qb, Kb, IPOUT);
  // V transpose (own kernel: 33KB LDS stays isolated)
  k_vtrans<<<dim3(20,24), blk, 0, stream>>>(rawV, rawEV, Vtb);
  // main attention (+ fused ip add on hid rows, defer-max)
  k_flash3<<<dim3(480), blk, 0, stream>>>(Qb, Kb, Vtb, IPOUT, AOUT);
  // epilogue projections: hid rows of AOUT already include ip contribution
  float* outp = (float*)d_out;
  k_gemm8_out<<<dim3(240), blk512, 0, stream>>>(AOUT + (size_t)STXT_*HID_, AOUT, Wb8, bo, bao, outp);
}